// Round 26
// baseline (196.010 us; speedup 1.0000x reference)
//
#include <hip/hip_runtime.h>
#include <hip/hip_bf16.h>

// Problem constants
constexpr int   DIMC  = 512;
constexpr int   PARTC = 6;
constexpr int   NTOK  = 162;
constexpr float SCALING = 22.62741699796952f; // sqrt(512)
constexpr float LNEPS   = 1e-5f;

typedef __attribute__((ext_vector_type(8))) short bf16x8;
typedef __attribute__((ext_vector_type(4))) float f32x4;

__device__ __forceinline__ unsigned int pack_bf16(float a, float b) {
  __hip_bfloat16 h0 = __float2bfloat16(a);
  __hip_bfloat16 h1 = __float2bfloat16(b);
  return (unsigned int)*(unsigned short*)&h0 |
         ((unsigned int)*(unsigned short*)&h1 << 16);
}
__device__ __forceinline__ float bf_lo(unsigned int u) {
  return __uint_as_float(u << 16);
}
__device__ __forceinline__ float bf_hi(unsigned int u) {
  return __uint_as_float(u & 0xffff0000u);
}

// ---------------------------------------------------------------------------
// K0: transpose f32 [R][C] -> bf16 [C][R]
// ---------------------------------------------------------------------------
__global__ __launch_bounds__(256) void transpose_f32_bf16(
    const float* __restrict__ in, __hip_bfloat16* __restrict__ outp, int R, int C)
{
  __shared__ float tile[32][33];
  const int tx = threadIdx.x, ty = threadIdx.y;
  const int bx = blockIdx.x, by = blockIdx.y;
  const int c = bx * 32 + tx;
#pragma unroll
  for (int i = 0; i < 32; i += 8) {
    int r = by * 32 + ty + i;
    tile[ty + i][tx] = in[(size_t)r * C + c];
  }
  __syncthreads();
#pragma unroll
  for (int i = 0; i < 32; i += 8) {
    outp[(size_t)(bx * 32 + ty + i) * R + by * 32 + tx] =
        __float2bfloat16(tile[tx][ty + i]);
  }
}

// ---------------------------------------------------------------------------
// S7: S6 + PART-SPLIT for occupancy.  Block = one b, 512 thr (8 waves).
// Wave w: token group q=w>>1 (tokens q, q+4, ...), part-half ph=w&1
// (parts 3ph..3ph+2).  Per-wave state: u[3][8]+ptp[3][4]+l[3] ~45 persistent
// regs (~70 peak) -> ~7 waves/SIMD by VGPR; 24.6KB LDS -> 4 blocks/CU
// resident (32-wave cap) ~2x S6 occupancy; serial chain per token halved.
// Each row read by the 2 waves of a part-half pair (L2-absorbed).
// Merge: 2-slot LDS two-phase add; LN epilogue thread-owns-dim(=tid).
// ---------------------------------------------------------------------------
__global__ __launch_bounds__(512, 4) void attn_ln_k(
    const float* __restrict__ x,     // [1024][162][512]
    const float* __restrict__ pt,    // [6][512]
    const float* __restrict__ g,     // [512]
    const float* __restrict__ bta,   // [512]
    __hip_bfloat16* __restrict__ outp)
{
  const int b = blockIdx.x;
  const int tid = threadIdx.x;       // 0..511
  const int w = tid >> 6;            // 0..7
  const int lane = tid & 63;
  const int q = w >> 1;              // token group 0..3
  const int ph = w & 1;              // part-half
  const int pbase = 3 * ph;
  const float* __restrict__ xb = x + (size_t)b * (NTOK * DIMC);

  __shared__ __align__(16) float ulds[2][PARTC][DIMC];  // 24 KB
  __shared__ float s_lw[8][3];
  __shared__ float s_red[8][2 * PARTC];

  // pt slice for this lane (dims [8l, 8l+8)) for 3 parts, packed bf16
  unsigned int ptp[3][4];
#pragma unroll
  for (int p = 0; p < 3; ++p) {
    const float* pr = pt + (pbase + p) * DIMC + 8 * lane;
    float4 a = *(const float4*)pr;
    float4 c = *(const float4*)(pr + 4);
    ptp[p][0] = pack_bf16(a.x, a.y);
    ptp[p][1] = pack_bf16(a.z, a.w);
    ptp[p][2] = pack_bf16(c.x, c.y);
    ptp[p][3] = pack_bf16(c.z, c.w);
  }

  float u[3][8];
  float l[3];
#pragma unroll
  for (int p = 0; p < 3; ++p) {
    l[p] = 0.f;
#pragma unroll
    for (int j = 0; j < 8; ++j) u[p][j] = 0.f;
  }

  // ---- single pass: logits + online PV accumulate (no barriers) ----
  for (int n = q; n < NTOK; n += 4) {
    const float* xr = xb + (size_t)n * DIMC + 8 * lane;
    f32x4 xa = __builtin_nontemporal_load((const f32x4*)xr);
    f32x4 xc = __builtin_nontemporal_load((const f32x4*)(xr + 4));

    float acc[3];
#pragma unroll
    for (int p = 0; p < 3; ++p) {
      acc[p] = xa[0] * bf_lo(ptp[p][0]) + xa[1] * bf_hi(ptp[p][0])
             + xa[2] * bf_lo(ptp[p][1]) + xa[3] * bf_hi(ptp[p][1])
             + xc[0] * bf_lo(ptp[p][2]) + xc[1] * bf_hi(ptp[p][2])
             + xc[2] * bf_lo(ptp[p][3]) + xc[3] * bf_hi(ptp[p][3]);
    }
#pragma unroll
    for (int off = 32; off > 0; off >>= 1) {
#pragma unroll
      for (int p = 0; p < 3; ++p) acc[p] += __shfl_xor(acc[p], off);
    }
#pragma unroll
    for (int p = 0; p < 3; ++p) {
      const float we = __expf(acc[p]);   // fixed-max softmax (M=0)
      l[p] += we;
      u[p][0] += we * xa[0]; u[p][1] += we * xa[1];
      u[p][2] += we * xa[2]; u[p][3] += we * xa[3];
      u[p][4] += we * xc[0]; u[p][5] += we * xc[1];
      u[p][6] += we * xc[2]; u[p][7] += we * xc[3];
    }
  }

  // ---- merge: phase 1 (waves 4..7 write), phase 2 (waves 0..3 add) ----
  if (lane == 0) {
#pragma unroll
    for (int p = 0; p < 3; ++p) s_lw[w][p] = l[p];
  }
  if (w >= 4) {
    const int slot = (w - 4) >> 1;
#pragma unroll
    for (int p = 0; p < 3; ++p) {
      *(float4*)&ulds[slot][pbase + p][8 * lane]     = make_float4(u[p][0], u[p][1], u[p][2], u[p][3]);
      *(float4*)&ulds[slot][pbase + p][8 * lane + 4] = make_float4(u[p][4], u[p][5], u[p][6], u[p][7]);
    }
  }
  __syncthreads();
  if (w < 4) {
    const int slot = w >> 1;
#pragma unroll
    for (int p = 0; p < 3; ++p) {
      float4 a = *(const float4*)&ulds[slot][pbase + p][8 * lane];
      float4 c = *(const float4*)&ulds[slot][pbase + p][8 * lane + 4];
      a.x += u[p][0]; a.y += u[p][1]; a.z += u[p][2]; a.w += u[p][3];
      c.x += u[p][4]; c.y += u[p][5]; c.z += u[p][6]; c.w += u[p][7];
      *(float4*)&ulds[slot][pbase + p][8 * lane]     = a;
      *(float4*)&ulds[slot][pbase + p][8 * lane + 4] = c;
    }
  }
  __syncthreads();

  // ---- epilogue: thread owns dim d = tid; y = u/(l*sqrt(512)); LN ----
  float lt[PARTC];
#pragma unroll
  for (int p = 0; p < PARTC; ++p) {
    const int phv = p / 3, lp = p - 3 * phv;
    lt[p] = s_lw[phv][lp] + s_lw[phv + 2][lp] + s_lw[phv + 4][lp] + s_lw[phv + 6][lp];
  }

  float y0[PARTC], s1[PARTC], s2[PARTC];
#pragma unroll
  for (int p = 0; p < PARTC; ++p) {
    const float uu = ulds[0][p][tid] + ulds[1][p][tid];
    const float inv = 1.f / (lt[p] * SCALING);
    y0[p] = uu * inv;
    s1[p] = y0[p];
    s2[p] = y0[p] * y0[p];
  }
#pragma unroll
  for (int off = 32; off > 0; off >>= 1) {
#pragma unroll
    for (int p = 0; p < PARTC; ++p) {
      s1[p] += __shfl_xor(s1[p], off);
      s2[p] += __shfl_xor(s2[p], off);
    }
  }
  if (lane == 0) {
#pragma unroll
    for (int p = 0; p < PARTC; ++p) {
      s_red[w][p] = s1[p];
      s_red[w][PARTC + p] = s2[p];
    }
  }
  __syncthreads();

  const float ga = g[tid], ba = bta[tid];
  __hip_bfloat16* orow = outp + (size_t)b * PARTC * DIMC;
#pragma unroll
  for (int p = 0; p < PARTC; ++p) {
    float S = 0.f, Q = 0.f;
#pragma unroll
    for (int ww = 0; ww < 8; ++ww) {
      S += s_red[ww][p];
      Q += s_red[ww][PARTC + p];
    }
    float mu = S * (1.f / 512.f);
    float var = Q * (1.f / 512.f) - mu * mu;
    float r = rsqrtf(var + LNEPS);
    orow[p * DIMC + tid] = __float2bfloat16((y0[p] - mu) * r * ga + ba);
  }
}

// ---------------------------------------------------------------------------
// MFMA GEMM: C[M][N] = act(A[M][K] @ Bt[N][K]^T + bias)   (unchanged)
// ---------------------------------------------------------------------------
template <int BM, int BN, bool GELU>
__global__ __launch_bounds__(256) void gemm_bt(
    const __hip_bfloat16* __restrict__ A,
    const __hip_bfloat16* __restrict__ Bt,
    const float* __restrict__ bias,
    void* __restrict__ Cv,
    int M, int N, int K)
{
  constexpr int BK = 64;
  constexpr int LDT = BK + 16; // 80 bf16 = 160B row stride
  __shared__ __align__(16) unsigned short Al[BM][LDT];
  __shared__ __align__(16) unsigned short Bl[BN][LDT];

  const int tid = threadIdx.x;
  const int w = tid >> 6, lane = tid & 63;
  const int wr = w >> 1, wc = w & 1;
  const int tm = blockIdx.y * BM, tn = blockIdx.x * BN;
  constexpr int FM = BM / 32, FN = BN / 32;

  f32x4 acc[FM][FN];
#pragma unroll
  for (int m = 0; m < FM; ++m)
#pragma unroll
    for (int n = 0; n < FN; ++n) acc[m][n] = (f32x4){0.f, 0.f, 0.f, 0.f};

  const int srow = tid >> 3;        // 0..31
  const int scol = (tid & 7) * 8;   // element offset in K

  for (int k0 = 0; k0 < K; k0 += BK) {
    __syncthreads();
#pragma unroll
    for (int r = 0; r < BM / 32; ++r) {
      int row = r * 32 + srow;
      *(int4*)(&Al[row][scol]) =
          *(const int4*)(A + (size_t)(tm + row) * K + k0 + scol);
    }
#pragma unroll
    for (int r = 0; r < BN / 32; ++r) {
      int row = r * 32 + srow;
      *(int4*)(&Bl[row][scol]) =
          *(const int4*)(Bt + (size_t)(tn + row) * K + k0 + scol);
    }
    __syncthreads();

#pragma unroll
    for (int kk = 0; kk < 2; ++kk) {
      const int ko = kk * 32 + (lane >> 4) * 8;
      bf16x8 af[FM], bfr[FN];
#pragma unroll
      for (int m = 0; m < FM; ++m)
        af[m] = *(const bf16x8*)(&Al[wr * (BM / 2) + m * 16 + (lane & 15)][ko]);
#pragma unroll
      for (int n = 0; n < FN; ++n)
        bfr[n] = *(const bf16x8*)(&Bl[wc * (BN / 2) + n * 16 + (lane & 15)][ko]);
#pragma unroll
      for (int m = 0; m < FM; ++m)
#pragma unroll
        for (int n = 0; n < FN; ++n)
          acc[m][n] = __builtin_amdgcn_mfma_f32_16x16x32_bf16(
              af[m], bfr[n], acc[m][n], 0, 0, 0);
    }
  }

  // Epilogue: C/D layout col = lane&15, row = (lane>>4)*4 + r  [m89-verified]
  const int cl = lane & 15, rg = (lane >> 4) * 4;
#pragma unroll
  for (int m = 0; m < FM; ++m) {
#pragma unroll
    for (int n = 0; n < FN; ++n) {
      int col = tn + wc * (BN / 2) + n * 16 + cl;
      float bv = bias[col];
#pragma unroll
      for (int r = 0; r < 4; ++r) {
        int row = tm + wr * (BM / 2) + m * 16 + rg + r;
        float v = acc[m][n][r] + bv;
        if (GELU) {
          v = 0.5f * v * (1.f + erff(v * 0.7071067811865476f));
          ((__hip_bfloat16*)Cv)[(size_t)row * N + col] = __float2bfloat16(v);
        } else {
          ((float*)Cv)[(size_t)row * N + col] = v;
        }
      }
    }
  }
}

// ---------------------------------------------------------------------------
extern "C" void kernel_launch(void* const* d_in, const int* in_sizes, int n_in,
                              void* d_out, int out_size, void* d_ws, size_t ws_size,
                              hipStream_t stream)
{
  const float* x   = (const float*)d_in[0];
  const float* pt  = (const float*)d_in[1];
  const float* g   = (const float*)d_in[2];
  const float* bta = (const float*)d_in[3];
  const float* W1  = (const float*)d_in[4];
  const float* b1  = (const float*)d_in[5];
  const float* W2  = (const float*)d_in[6];
  const float* b2  = (const float*)d_in[7];
  float* outp = (float*)d_out;

  char* ws = (char*)d_ws;
  __hip_bfloat16* W1T = (__hip_bfloat16*)(ws);                    // 2048x512  bf16 (2 MB)
  __hip_bfloat16* W2T = (__hip_bfloat16*)(ws + 2097152);          // 512x2048  bf16 (2 MB)
  __hip_bfloat16* LNO = (__hip_bfloat16*)(ws + 4194304);          // 6144x512  bf16 (6 MB)
  __hip_bfloat16* H   = (__hip_bfloat16*)(ws + 10485760);         // 6144x2048 bf16 (25 MB)

  // K0: W1 (512x2048) -> W1T (2048x512); W2 (2048x512) -> W2T (512x2048)
  transpose_f32_bf16<<<dim3(2048 / 32, 512 / 32), dim3(32, 8), 0, stream>>>(W1, W1T, 512, 2048);
  transpose_f32_bf16<<<dim3(512 / 32, 2048 / 32), dim3(32, 8), 0, stream>>>(W2, W2T, 2048, 512);

  // S7: single-pass fused attention + LN -> LNO (part-split, 8 waves/block)
  attn_ln_k<<<1024, 512, 0, stream>>>(x, pt, g, bta, LNO);

  // K2: h = gelu(LNO @ W1 + b1) -> H (bf16)
  gemm_bt<128, 128, true><<<dim3(2048 / 128, 6144 / 128), 256, 0, stream>>>(
      LNO, W1T, b1, (void*)H, 6144, 2048, 512);

  // K3: out = H @ W2 + b2 -> d_out (f32)  — BM=128: 16 MFMAs/K-step
  gemm_bt<128, 64, false><<<dim3(512 / 64, 6144 / 128), 256, 0, stream>>>(
      H, W2T, b2, (void*)outp, 6144, 512, 2048);
}

// Round 27
// 169.750 us; speedup vs baseline: 1.1547x; 1.1547x over previous
//
#include <hip/hip_runtime.h>
#include <hip/hip_bf16.h>

// Problem constants
constexpr int   DIMC  = 512;
constexpr int   PARTC = 6;
constexpr int   NTOK  = 162;
constexpr float SCALING = 22.62741699796952f; // sqrt(512)
constexpr float LNEPS   = 1e-5f;

typedef __attribute__((ext_vector_type(8))) short bf16x8;
typedef __attribute__((ext_vector_type(4))) float f32x4;

__device__ __forceinline__ unsigned int pack_bf16(float a, float b) {
  __hip_bfloat16 h0 = __float2bfloat16(a);
  __hip_bfloat16 h1 = __float2bfloat16(b);
  return (unsigned int)*(unsigned short*)&h0 |
         ((unsigned int)*(unsigned short*)&h1 << 16);
}
__device__ __forceinline__ float bf_lo(unsigned int u) {
  return __uint_as_float(u << 16);
}
__device__ __forceinline__ float bf_hi(unsigned int u) {
  return __uint_as_float(u & 0xffff0000u);
}

// async global->LDS, 16B per lane; LDS dest = wave-uniform base + lane*16
__device__ __forceinline__ void gload16h(const __hip_bfloat16* gp, unsigned short* lp) {
  __builtin_amdgcn_global_load_lds(
      (const __attribute__((address_space(1))) void*)gp,
      (__attribute__((address_space(3))) void*)lp, 16, 0, 0);
}

#define BAR_ALL() do { asm volatile("s_waitcnt vmcnt(0) lgkmcnt(0)" ::: "memory"); \
                       __builtin_amdgcn_sched_barrier(0);                          \
                       __builtin_amdgcn_s_barrier(); } while (0)

// ---------------------------------------------------------------------------
// K0: transpose f32 [R][C] -> bf16 [C][R]
// ---------------------------------------------------------------------------
__global__ __launch_bounds__(256) void transpose_f32_bf16(
    const float* __restrict__ in, __hip_bfloat16* __restrict__ outp, int R, int C)
{
  __shared__ float tile[32][33];
  const int tx = threadIdx.x, ty = threadIdx.y;
  const int bx = blockIdx.x, by = blockIdx.y;
  const int c = bx * 32 + tx;
#pragma unroll
  for (int i = 0; i < 32; i += 8) {
    int r = by * 32 + ty + i;
    tile[ty + i][tx] = in[(size_t)r * C + c];
  }
  __syncthreads();
#pragma unroll
  for (int i = 0; i < 32; i += 8) {
    outp[(size_t)(bx * 32 + ty + i) * R + by * 32 + tx] =
        __float2bfloat16(tile[tx][ty + i]);
  }
}

// ---------------------------------------------------------------------------
// S6 (R25 verbatim — best attn at 174.1 total): single-pass attention + LN.
// bf16-packed pt regs (24 VGPR), nt x loads, LB(256,4).
// ---------------------------------------------------------------------------
__global__ __launch_bounds__(256, 4) void attn_ln_k(
    const float* __restrict__ x,     // [1024][162][512]
    const float* __restrict__ pt,    // [6][512]
    const float* __restrict__ g,     // [512]
    const float* __restrict__ bta,   // [512]
    __hip_bfloat16* __restrict__ outp)
{
  const int b = blockIdx.x;
  const int tid = threadIdx.x;
  const int w = tid >> 6;
  const int lane = tid & 63;
  const float* __restrict__ xb = x + (size_t)b * (NTOK * DIMC);

  __shared__ __align__(16) float ulds[2][PARTC][DIMC];  // 24 KB
  __shared__ float s_lw[4][PARTC];
  __shared__ float s_red[4][2 * PARTC];

  // pt slice for this lane (dims [8l, 8l+8)) as packed bf16: 4 uints/part
  unsigned int ptp[PARTC][4];
#pragma unroll
  for (int p = 0; p < PARTC; ++p) {
    const float* pr = pt + p * DIMC + 8 * lane;
    float4 a = *(const float4*)pr;
    float4 c = *(const float4*)(pr + 4);
    ptp[p][0] = pack_bf16(a.x, a.y);
    ptp[p][1] = pack_bf16(a.z, a.w);
    ptp[p][2] = pack_bf16(c.x, c.y);
    ptp[p][3] = pack_bf16(c.z, c.w);
  }

  float u[PARTC][8];
  float l[PARTC];
#pragma unroll
  for (int p = 0; p < PARTC; ++p) {
    l[p] = 0.f;
#pragma unroll
    for (int j = 0; j < 8; ++j) u[p][j] = 0.f;
  }

  // ---- single pass: logits + online PV accumulate (no barriers) ----
  for (int n = w; n < NTOK; n += 4) {
    const float* xr = xb + (size_t)n * DIMC + 8 * lane;
    f32x4 xa = __builtin_nontemporal_load((const f32x4*)xr);
    f32x4 xc = __builtin_nontemporal_load((const f32x4*)(xr + 4));

    float acc[PARTC];
#pragma unroll
    for (int p = 0; p < PARTC; ++p) {
      acc[p] = xa[0] * bf_lo(ptp[p][0]) + xa[1] * bf_hi(ptp[p][0])
             + xa[2] * bf_lo(ptp[p][1]) + xa[3] * bf_hi(ptp[p][1])
             + xc[0] * bf_lo(ptp[p][2]) + xc[1] * bf_hi(ptp[p][2])
             + xc[2] * bf_lo(ptp[p][3]) + xc[3] * bf_hi(ptp[p][3]);
    }
#pragma unroll
    for (int off = 32; off > 0; off >>= 1) {
#pragma unroll
      for (int p = 0; p < PARTC; ++p) acc[p] += __shfl_xor(acc[p], off);
    }
#pragma unroll
    for (int p = 0; p < PARTC; ++p) {
      const float we = __expf(acc[p]);   // fixed-max softmax (M=0)
      l[p] += we;
      u[p][0] += we * xa[0]; u[p][1] += we * xa[1];
      u[p][2] += we * xa[2]; u[p][3] += we * xa[3];
      u[p][4] += we * xc[0]; u[p][5] += we * xc[1];
      u[p][6] += we * xc[2]; u[p][7] += we * xc[3];
    }
  }

  // ---- merge the 4 waves' partial (u, l) ----
  if (w >= 2) {
#pragma unroll
    for (int p = 0; p < PARTC; ++p) {
      *(float4*)&ulds[w - 2][p][8 * lane]     = make_float4(u[p][0], u[p][1], u[p][2], u[p][3]);
      *(float4*)&ulds[w - 2][p][8 * lane + 4] = make_float4(u[p][4], u[p][5], u[p][6], u[p][7]);
    }
    if (lane == 0) {
#pragma unroll
      for (int p = 0; p < PARTC; ++p) s_lw[w][p] = l[p];
    }
  }
  __syncthreads();
  if (w < 2) {
#pragma unroll
    for (int p = 0; p < PARTC; ++p) {
      float4 a = *(const float4*)&ulds[w][p][8 * lane];
      float4 c = *(const float4*)&ulds[w][p][8 * lane + 4];
      a.x += u[p][0]; a.y += u[p][1]; a.z += u[p][2]; a.w += u[p][3];
      c.x += u[p][4]; c.y += u[p][5]; c.z += u[p][6]; c.w += u[p][7];
      *(float4*)&ulds[w][p][8 * lane]     = a;
      *(float4*)&ulds[w][p][8 * lane + 4] = c;
    }
    if (lane == 0) {
#pragma unroll
      for (int p = 0; p < PARTC; ++p) s_lw[w][p] = l[p];
    }
  }
  __syncthreads();

  // ---- epilogue: thread owns dims (2t, 2t+1); y = u/(l*sqrt(512)); LN ----
  float lt[PARTC];
#pragma unroll
  for (int p = 0; p < PARTC; ++p)
    lt[p] = s_lw[0][p] + s_lw[1][p] + s_lw[2][p] + s_lw[3][p];

  float y0[PARTC], y1[PARTC], s1[PARTC], s2[PARTC];
#pragma unroll
  for (int p = 0; p < PARTC; ++p) {
    const float uu0 = ulds[0][p][2 * tid]     + ulds[1][p][2 * tid];
    const float uu1 = ulds[0][p][2 * tid + 1] + ulds[1][p][2 * tid + 1];
    const float inv = 1.f / (lt[p] * SCALING);
    y0[p] = uu0 * inv;
    y1[p] = uu1 * inv;
    s1[p] = y0[p] + y1[p];
    s2[p] = y0[p] * y0[p] + y1[p] * y1[p];
  }
#pragma unroll
  for (int off = 32; off > 0; off >>= 1) {
#pragma unroll
    for (int p = 0; p < PARTC; ++p) {
      s1[p] += __shfl_xor(s1[p], off);
      s2[p] += __shfl_xor(s2[p], off);
    }
  }
  if (lane == 0) {
#pragma unroll
    for (int p = 0; p < PARTC; ++p) {
      s_red[w][p] = s1[p];
      s_red[w][PARTC + p] = s2[p];
    }
  }
  __syncthreads();

  const float ga0 = g[2 * tid], ga1 = g[2 * tid + 1];
  const float bb0 = bta[2 * tid], bb1 = bta[2 * tid + 1];
  __hip_bfloat16* orow = outp + (size_t)b * PARTC * DIMC;
#pragma unroll
  for (int p = 0; p < PARTC; ++p) {
    float S = s_red[0][p] + s_red[1][p] + s_red[2][p] + s_red[3][p];
    float Q = s_red[0][PARTC + p] + s_red[1][PARTC + p] + s_red[2][PARTC + p] + s_red[3][PARTC + p];
    float mu = S * (1.f / 512.f);
    float var = Q * (1.f / 512.f) - mu * mu;
    float r = rsqrtf(var + LNEPS);
    __hip_bfloat162 hv;
    hv.x = __float2bfloat16((y0[p] - mu) * r * ga0 + bb0);
    hv.y = __float2bfloat16((y1[p] - mu) * r * ga1 + bb1);
    *(__hip_bfloat162*)(orow + p * DIMC + 2 * tid) = hv;
  }
}

// ---------------------------------------------------------------------------
// MFMA GEMM v2: global_load_lds staging (m97-style), linear LDS [.][64].
// Each wave issues BM/32 (resp BN/32) 1KB stages: lane l -> row l/8,
// 16B chunk l%8 (matches HW base+lane*16 LDS write).  vmcnt(0) barrier,
// then identical MFMA fragment reads (LDT=64).
// ---------------------------------------------------------------------------
template <int BM, int BN, bool GELU>
__global__ __launch_bounds__(256) void gemm_bt(
    const __hip_bfloat16* __restrict__ A,
    const __hip_bfloat16* __restrict__ Bt,
    const float* __restrict__ bias,
    void* __restrict__ Cv,
    int M, int N, int K)
{
  constexpr int BK = 64;
  __shared__ __align__(16) unsigned short Al[BM][BK];
  __shared__ __align__(16) unsigned short Bl[BN][BK];

  const int tid = threadIdx.x;
  const int w = tid >> 6, lane = tid & 63;
  const int wr = w >> 1, wc = w & 1;
  const int tm = blockIdx.y * BM, tn = blockIdx.x * BN;
  constexpr int FM = BM / 32, FN = BN / 32;

  f32x4 acc[FM][FN];
#pragma unroll
  for (int m = 0; m < FM; ++m)
#pragma unroll
    for (int n = 0; n < FN; ++n) acc[m][n] = (f32x4){0.f, 0.f, 0.f, 0.f};

  const int lrow = lane >> 3;        // 0..7 (row within 8-row stage)
  const int lcol = (lane & 7) * 8;   // element offset (16B chunk)

  for (int k0 = 0; k0 < K; k0 += BK) {
    __syncthreads();   // prior-iteration LDS reads done
#pragma unroll
    for (int i = 0; i < BM / 32; ++i) {
      const int r0 = w * (BM / 4) + i * 8;
      gload16h(A + (size_t)(tm + r0 + lrow) * K + k0 + lcol, &Al[r0][0]);
    }
#pragma unroll
    for (int i = 0; i < BN / 32; ++i) {
      const int r0 = w * (BN / 4) + i * 8;
      gload16h(Bt + (size_t)(tn + r0 + lrow) * K + k0 + lcol, &Bl[r0][0]);
    }
    BAR_ALL();   // stages landed in LDS

#pragma unroll
    for (int kk = 0; kk < 2; ++kk) {
      const int ko = kk * 32 + (lane >> 4) * 8;
      bf16x8 af[FM], bfr[FN];
#pragma unroll
      for (int m = 0; m < FM; ++m)
        af[m] = *(const bf16x8*)(&Al[wr * (BM / 2) + m * 16 + (lane & 15)][ko]);
#pragma unroll
      for (int n = 0; n < FN; ++n)
        bfr[n] = *(const bf16x8*)(&Bl[wc * (BN / 2) + n * 16 + (lane & 15)][ko]);
#pragma unroll
      for (int m = 0; m < FM; ++m)
#pragma unroll
        for (int n = 0; n < FN; ++n)
          acc[m][n] = __builtin_amdgcn_mfma_f32_16x16x32_bf16(
              af[m], bfr[n], acc[m][n], 0, 0, 0);
    }
  }

  // Epilogue: C/D layout col = lane&15, row = (lane>>4)*4 + r  [m89-verified]
  const int cl = lane & 15, rg = (lane >> 4) * 4;
#pragma unroll
  for (int m = 0; m < FM; ++m) {
#pragma unroll
    for (int n = 0; n < FN; ++n) {
      int col = tn + wc * (BN / 2) + n * 16 + cl;
      float bv = bias[col];
#pragma unroll
      for (int r = 0; r < 4; ++r) {
        int row = tm + wr * (BM / 2) + m * 16 + rg + r;
        float v = acc[m][n][r] + bv;
        if (GELU) {
          v = 0.5f * v * (1.f + erff(v * 0.7071067811865476f));
          ((__hip_bfloat16*)Cv)[(size_t)row * N + col] = __float2bfloat16(v);
        } else {
          ((float*)Cv)[(size_t)row * N + col] = v;
        }
      }
    }
  }
}

// ---------------------------------------------------------------------------
extern "C" void kernel_launch(void* const* d_in, const int* in_sizes, int n_in,
                              void* d_out, int out_size, void* d_ws, size_t ws_size,
                              hipStream_t stream)
{
  const float* x   = (const float*)d_in[0];
  const float* pt  = (const float*)d_in[1];
  const float* g   = (const float*)d_in[2];
  const float* bta = (const float*)d_in[3];
  const float* W1  = (const float*)d_in[4];
  const float* b1  = (const float*)d_in[5];
  const float* W2  = (const float*)d_in[6];
  const float* b2  = (const float*)d_in[7];
  float* outp = (float*)d_out;

  char* ws = (char*)d_ws;
  __hip_bfloat16* W1T = (__hip_bfloat16*)(ws);                    // 2048x512  bf16 (2 MB)
  __hip_bfloat16* W2T = (__hip_bfloat16*)(ws + 2097152);          // 512x2048  bf16 (2 MB)
  __hip_bfloat16* LNO = (__hip_bfloat16*)(ws + 4194304);          // 6144x512  bf16 (6 MB)
  __hip_bfloat16* H   = (__hip_bfloat16*)(ws + 10485760);         // 6144x2048 bf16 (25 MB)

  // K0: W1 (512x2048) -> W1T (2048x512); W2 (2048x512) -> W2T (512x2048)
  transpose_f32_bf16<<<dim3(2048 / 32, 512 / 32), dim3(32, 8), 0, stream>>>(W1, W1T, 512, 2048);
  transpose_f32_bf16<<<dim3(512 / 32, 2048 / 32), dim3(32, 8), 0, stream>>>(W2, W2T, 2048, 512);

  // S6: single-pass fused attention + LN -> LNO (R25 verbatim)
  attn_ln_k<<<1024, 256, 0, stream>>>(x, pt, g, bta, LNO);

  // K2: h = gelu(LNO @ W1 + b1) -> H (bf16)
  gemm_bt<128, 128, true><<<dim3(2048 / 128, 6144 / 128), 256, 0, stream>>>(
      LNO, W1T, b1, (void*)H, 6144, 2048, 512);

  // K3: out = H @ W2 + b2 -> d_out (f32)
  gemm_bt<128, 64, false><<<dim3(512 / 64, 6144 / 128), 256, 0, stream>>>(
      H, W2T, b2, (void*)outp, 6144, 512, 2048);
}